// Round 9
// baseline (173.618 us; speedup 1.0000x reference)
//
#include <hip/hip_runtime.h>
#include <math.h>

#define NB 2
#define NH 8
#define SS 160
#define DD 64
#define MFIX 40.0f
#define NMFIXL2 -57.70780163555852f   // -MFIX * log2(e)
#define LOG2E  1.4426950408889634f

// LDS map (110400 B, 1 block/CU):
//   K2H [0,20480)       [160 t][8 grp] bf16-hi, slot g^(t&7)  (staged ONCE)
//   K2L [20480,40960)   bf16-lo
//   K1F [40960,43520)   [10 s][64 d] f32 (staged ONCE)
//   A1L [43520,56640)   [2 jh][10 sl][164 q] f32 row sums (direct stores)
//   A2  [56640,110400)  5 x [32 q][168 t] bf16
//   V2T [0,21504)       [64 d][168 t] bf16 — epilogue only, aliases dead K2
// Main loop: NO LDS writes except wave-private A1L -> NO barriers in loop.
// Register discipline (empirical budget ~84 arch + ~84 accum): Q kept as bf16
// hi/lo packed words (16 VGPR, proven fit in R2/R7); f32 Q (32 VGPR, R8) or
// pinned k2 (+40, R5/6) SPILLS ~100-300 MB scratch. Reconstruct q = qh+ql on
// the fly (3 VALU/elem) in the per-tile A-frag build.
#define K2H_OFF  0
#define K2L_OFF  20480
#define K1F_OFF  40960
#define A1L_OFF  43520
#define A1L_STR  164
#define A1L_BANK 1640
#define A2_OFF   56640
#define A2_ROWB  336
#define A2_BLKB  10752
#define V2T_OFF  0
#define V2T_ROWB 336
#define HIMASK   0xffff0000u

typedef __attribute__((ext_vector_type(8))) short bf16x8;
typedef __attribute__((ext_vector_type(4))) float f32x4;

#define MFMA16(a, b, c) __builtin_amdgcn_mfma_f32_16x16x32_bf16(a, b, c, 0, 0, 0)

// split a pair of fp32 into packed bf16 (hi, lo); lo captures the residual.
__device__ __forceinline__ uint2 splitpair(float a0, float a1) {
    unsigned u0 = __float_as_uint(a0), u1 = __float_as_uint(a1);
    unsigned hi = (u0 >> 16) | (u1 & HIMASK);
    float r0 = a0 - __uint_as_float(u0 & HIMASK);
    float r1 = a1 - __uint_as_float(u1 & HIMASK);
    unsigned v0 = __float_as_uint(r0), v1 = __float_as_uint(r1);
    unsigned lo = (v0 >> 16) | (v1 & HIMASK);
    return make_uint2(hi, lo);
}

// scores[q,(s,t)] = sum_d (q[q,d]*log2e*k1[s,d]) * k2[t,d].
// B = k2 hi/lo staged once; per tile the A-frag (q*k1[sl]) is built in regs
// from bf16-pair Q (reconstructed) and a broadcast LDS read of k1[sl].
__global__ __launch_bounds__(640) void tritt_k1(
    const float* __restrict__ q,  const float* __restrict__ k1,
    const float* __restrict__ k2, const float* __restrict__ v1,
    const float* __restrict__ v2, float* __restrict__ zp, float* __restrict__ lp)
{
    __shared__ __align__(16) char sm[110400];

    const int tid  = threadIdx.x;
    const int bh   = blockIdx.x >> 4;
    const int ck   = blockIdx.x & 15;        // s-chunk: s = ck*10 + sl
    const size_t base = (size_t)bh * SS * DD;
    const int sbase = ck * 10;

    const int lane = tid & 63, wid = tid >> 6;
    const int n16  = lane & 15, quad = lane >> 4;
    const int mrow = wid >> 1;               // q strip 32*mrow .. +31
    const int jh   = wid & 1;                // t half: j = 5*jh + jj

    // ---- prologue staging (once per block) ----
    // K2 split hi/lo: 1280 (t, 8-d-group) groups
    #pragma unroll
    for (int it = 0; it < 2; ++it) {
        int f = tid + 640 * it;
        int t = f >> 3, g = f & 7;
        const float4* y = (const float4*)(k2 + base + (size_t)t * DD + g * 8);
        float4 y0 = y[0], y1 = y[1];
        uint2 p0 = splitpair(y0.x, y0.y);
        uint2 p1 = splitpair(y0.z, y0.w);
        uint2 p2 = splitpair(y1.x, y1.y);
        uint2 p3 = splitpair(y1.z, y1.w);
        char* d = sm + t * 128 + ((g ^ (t & 7)) * 16);
        *(uint4*)(d + K2H_OFF) = make_uint4(p0.x, p1.x, p2.x, p3.x);
        *(uint4*)(d + K2L_OFF) = make_uint4(p0.y, p1.y, p2.y, p3.y);
    }
    // K1 raw copy: this block's 10 rows, one f32 per thread
    {
        int r = tid >> 6, c = tid & 63;
        float v = k1[base + (size_t)(sbase + r) * DD + c];
        *(float*)(sm + K1F_OFF + r * 256 + c * 4) = v;
    }
    // Q as bf16 hi/lo packed words, pre-scaled by log2e (16 VGPRs, persistent)
    uint4 qhw[2][2], qlw[2][2];
    #pragma unroll
    for (int m = 0; m < 2; ++m)
        #pragma unroll
        for (int kc = 0; kc < 2; ++kc) {
            const float4* qp = (const float4*)(q + base
                + (size_t)(32*mrow + 16*m + n16) * DD + kc*32 + quad*8);
            float4 a = qp[0], b = qp[1];
            uint2 p0 = splitpair(a.x*LOG2E, a.y*LOG2E), p1 = splitpair(a.z*LOG2E, a.w*LOG2E);
            uint2 p2 = splitpair(b.x*LOG2E, b.y*LOG2E), p3 = splitpair(b.z*LOG2E, b.w*LOG2E);
            qhw[m][kc] = make_uint4(p0.x, p1.x, p2.x, p3.x);
            qlw[m][kc] = make_uint4(p0.y, p1.y, p2.y, p3.y);
        }
    float* A1L = (float*)(sm + A1L_OFF);
    __syncthreads();                          // LDS K2/K1F ready

    f32x4 a2run[2][5];
    #pragma unroll
    for (int m = 0; m < 2; ++m)
        #pragma unroll
        for (int jj = 0; jj < 5; ++jj) a2run[m][jj] = (f32x4){0.f,0.f,0.f,0.f};

    // ---- main loop: 10 s-tiles, NO barriers ----
    #pragma unroll 1
    for (int sl = 0; sl < 10; ++sl) {
        f32x4 acc[2][5];
        #pragma unroll
        for (int m = 0; m < 2; ++m)
            #pragma unroll
            for (int jj = 0; jj < 5; ++jj)
                acc[m][jj] = (f32x4){NMFIXL2, NMFIXL2, NMFIXL2, NMFIXL2};

        #pragma unroll
        for (int kc = 0; kc < 2; ++kc) {
            // k1[sl] broadcast read (uniform across n16 -> free)
            const float4* kv = (const float4*)(sm + K1F_OFF + sl*256 + kc*128 + quad*32);
            float4 kA = kv[0], kB = kv[1];
            // A-frags in regs: reconstruct q = qh+ql, multiply k1, split hi/lo
            bf16x8 ah[2], al[2];
            #pragma unroll
            for (int m = 0; m < 2; ++m) {
                uint4 H = qhw[m][kc], L = qlw[m][kc];
                float e0, e1;
                e0 = __uint_as_float(H.x << 16) + __uint_as_float(L.x << 16);
                e1 = __uint_as_float(H.x & HIMASK) + __uint_as_float(L.x & HIMASK);
                uint2 s0 = splitpair(e0 * kA.x, e1 * kA.y);
                e0 = __uint_as_float(H.y << 16) + __uint_as_float(L.y << 16);
                e1 = __uint_as_float(H.y & HIMASK) + __uint_as_float(L.y & HIMASK);
                uint2 s1 = splitpair(e0 * kA.z, e1 * kA.w);
                e0 = __uint_as_float(H.z << 16) + __uint_as_float(L.z << 16);
                e1 = __uint_as_float(H.z & HIMASK) + __uint_as_float(L.z & HIMASK);
                uint2 s2 = splitpair(e0 * kB.x, e1 * kB.y);
                e0 = __uint_as_float(H.w << 16) + __uint_as_float(L.w << 16);
                e1 = __uint_as_float(H.w & HIMASK) + __uint_as_float(L.w & HIMASK);
                uint2 s3 = splitpair(e0 * kB.z, e1 * kB.w);
                uint4 hh = make_uint4(s0.x, s1.x, s2.x, s3.x);
                uint4 ll = make_uint4(s0.y, s1.y, s2.y, s3.y);
                ah[m] = *(bf16x8*)&hh;
                al[m] = *(bf16x8*)&ll;
            }
            const int slot = ((4*kc + quad) ^ (n16 & 7)) * 16;
            #pragma unroll
            for (int jj = 0; jj < 5; ++jj) {
                const char* rb = sm + (16*(5*jh + jj) + n16) * 128 + slot;
                bf16x8 bh8 = *(const bf16x8*)(rb + K2H_OFF);
                bf16x8 bl8 = *(const bf16x8*)(rb + K2L_OFF);
                #pragma unroll
                for (int m = 0; m < 2; ++m) {
                    acc[m][jj] = MFMA16(ah[m], bh8, acc[m][jj]);
                    acc[m][jj] = MFMA16(al[m], bh8, acc[m][jj]);
                    acc[m][jj] = MFMA16(ah[m], bl8, acc[m][jj]);
                }
            }
        }

        // exp2 (shift folded into acc init); accumulate A2 + row partials
        float prs[2][4] = {{0,0,0,0},{0,0,0,0}};
        #pragma unroll
        for (int m = 0; m < 2; ++m)
            #pragma unroll
            for (int jj = 0; jj < 5; ++jj)
                #pragma unroll
                for (int r = 0; r < 4; ++r) {
                    float e = exp2f(acc[m][jj][r]);
                    a2run[m][jj][r] += e;
                    prs[m][r] += e;
                }
        // row sums over this jh-half: reduce over n16, direct store (2 banks)
        #pragma unroll
        for (int m = 0; m < 2; ++m)
            #pragma unroll
            for (int r = 0; r < 4; ++r) {
                float v = prs[m][r];
                v += __shfl_xor(v, 1, 64); v += __shfl_xor(v, 2, 64);
                v += __shfl_xor(v, 4, 64); v += __shfl_xor(v, 8, 64);
                if (n16 == 0)
                    A1L[jh*A1L_BANK + sl*A1L_STR + 32*mrow + 16*m + 4*quad + r] = v;
            }
    }

    // ---- epilogue: A2 regs -> LDS bf16 (A-frag layout) ----
    #pragma unroll
    for (int m = 0; m < 2; ++m)
        #pragma unroll
        for (int jj = 0; jj < 5; ++jj)
            #pragma unroll
            for (int r = 0; r < 4; ++r) {
                unsigned u = (__float_as_uint(a2run[m][jj][r]) + 0x8000u) >> 16;
                *(unsigned short*)(sm + A2_OFF + mrow*A2_BLKB
                    + (16*m + 4*quad + r)*A2_ROWB
                    + (16*(5*jh + jj) + n16)*2) = (unsigned short)u;
            }
    __syncthreads();    // all A1L/A2 settled; K2 region now dead

    // V2T staging (aliases dead K2): v2 -> [64 d][168 t] bf16
    {
        int t = tid >> 2, d0 = (tid & 3) * 16;
        const float4* vp = (const float4*)(v2 + base + (size_t)t * DD + d0);
        float4 a0 = vp[0], a1 = vp[1], a2v = vp[2], a3 = vp[3];
        float vals[16] = {a0.x,a0.y,a0.z,a0.w, a1.x,a1.y,a1.z,a1.w,
                          a2v.x,a2v.y,a2v.z,a2v.w, a3.x,a3.y,a3.z,a3.w};
        #pragma unroll
        for (int i = 0; i < 16; ++i) {
            unsigned u = (__float_as_uint(vals[i]) + 0x8000u) >> 16;
            *(unsigned short*)(sm + V2T_OFF + (size_t)(d0 + i)*V2T_ROWB + t*2)
                = (unsigned short)u;
        }
    }
    if (tid < SS) {
        float l = 0.f;
        #pragma unroll
        for (int s2 = 0; s2 < 10; ++s2)
            l += A1L[s2*A1L_STR + tid] + A1L[A1L_BANK + s2*A1L_STR + tid];
        lp[(size_t)(bh*16 + ck)*SS + tid] = l;
    }
    __syncthreads();

    // ---- PV: zp[q,d] = A2 @ v2 (MFMA, K=160) + A1 @ v1 (VALU) ----
    f32x4 zacc[4];
    #pragma unroll
    for (int jd = 0; jd < 4; ++jd) zacc[jd] = (f32x4){0.f,0.f,0.f,0.f};

    const char* apv = sm + A2_OFF + (wid >> 1)*A2_BLKB + ((wid & 1)*16 + n16)*A2_ROWB;
    #pragma unroll
    for (int kc = 0; kc < 5; ++kc) {
        bf16x8 af = *(const bf16x8*)(apv + (kc*32 + quad*8)*2);
        #pragma unroll
        for (int jd = 0; jd < 4; ++jd) {
            bf16x8 bfr = *(const bf16x8*)(sm + V2T_OFF + (16*jd + n16)*V2T_ROWB
                                          + (kc*32 + quad*8)*2);
            zacc[jd] = MFMA16(af, bfr, zacc[jd]);
        }
    }
    const float* v1p = v1 + base + (size_t)sbase * DD;
    #pragma unroll 1
    for (int s2 = 0; s2 < 10; ++s2) {
        int qrow = 16*wid + 4*quad;
        float a10 = A1L[s2*A1L_STR + qrow + 0] + A1L[A1L_BANK + s2*A1L_STR + qrow + 0];
        float a11 = A1L[s2*A1L_STR + qrow + 1] + A1L[A1L_BANK + s2*A1L_STR + qrow + 1];
        float a12 = A1L[s2*A1L_STR + qrow + 2] + A1L[A1L_BANK + s2*A1L_STR + qrow + 2];
        float a13 = A1L[s2*A1L_STR + qrow + 3] + A1L[A1L_BANK + s2*A1L_STR + qrow + 3];
        #pragma unroll
        for (int jd = 0; jd < 4; ++jd) {
            float vvv = v1p[s2*DD + 16*jd + n16];
            zacc[jd][0] = fmaf(a10, vvv, zacc[jd][0]);
            zacc[jd][1] = fmaf(a11, vvv, zacc[jd][1]);
            zacc[jd][2] = fmaf(a12, vvv, zacc[jd][2]);
            zacc[jd][3] = fmaf(a13, vvv, zacc[jd][3]);
        }
    }
    float* zpb = zp + (size_t)(bh*16 + ck) * SS * DD;
    #pragma unroll
    for (int jd = 0; jd < 4; ++jd)
        #pragma unroll
        for (int r = 0; r < 4; ++r)
            zpb[(16*wid + 4*quad + r)*DD + 16*jd + n16] = zacc[jd][r];
}

__global__ __launch_bounds__(256) void tritt_k2(
    const float* __restrict__ zp, const float* __restrict__ lp,
    float* __restrict__ out)
{
    int b  = blockIdx.x;                 // 640 blocks: (bh, 4-q group)
    int bh = b / 40;
    int qq = (b % 40)*4 + (threadIdx.x >> 6);
    int d  = threadIdx.x & 63;
    float zs = 0.f, ls = 0.f;
    #pragma unroll 1
    for (int c = 0; c < 16; ++c) {
        zs += zp[((size_t)(bh*16 + c)*SS + qq)*DD + d];
        ls += lp[(size_t)(bh*16 + c)*SS + qq];
    }
    out[((size_t)bh*SS + qq)*DD + d] = zs / ls;
    if (d == 0)
        out[(size_t)NB*NH*SS*DD + (size_t)bh*SS + qq] = MFIX + __logf(ls);
}

// ====================== fallback (round-1 kernel, verified) ======================
#define FNT 640
#define FNW 10
__global__ __launch_bounds__(FNT, 5) void tritt_fallback(
    const float* __restrict__ q,  const float* __restrict__ k1,
    const float* __restrict__ k2, const float* __restrict__ v1,
    const float* __restrict__ v2, float* __restrict__ out)
{
    __shared__ __align__(16) char sm[40960];
    const int tid = threadIdx.x;
    const int blk = blockIdx.x;
    const int bh  = blk / SS;
    const int qi  = blk % SS;
    const size_t base = (size_t)bh * SS * DD;
    const float4* k1f = (const float4*)(k1 + base);
    const float4* k2f = (const float4*)(k2 + base);
    const float4* qf  = (const float4*)(q + base + (size_t)qi * DD);
    const int lane = tid & 63;
    const int wid  = tid >> 6;
    const int n16  = lane & 15, quad = lane >> 4;
    const int s0   = 16 * wid;
    const int ssg  = tid >> 2;
    const int sgg  = tid & 3;
    const int soff = ssg * 64 + ((sgg ^ (ssg & 3)) * 16);
    const char* abase = sm + (s0 + n16) * 64 + ((quad ^ (n16 & 3)) * 16);
    const char* bbase = sm + 20480 + n16 * 64 + ((quad ^ (n16 & 3)) * 16);
    f32x4 acc[FNW];
    #pragma unroll
    for (int j = 0; j < FNW; ++j) acc[j] = (f32x4){0.f, 0.f, 0.f, 0.f};
    #pragma unroll
    for (int ks = 0; ks < 2; ++ks) {
        int fg = ssg * 16 + ks * 8 + sgg * 2;
        float4 x0 = k1f[fg], x1 = k1f[fg + 1];
        float4 y0 = k2f[fg], y1 = k2f[fg + 1];
        float4 q0 = qf[ks * 8 + sgg * 2], q1 = qf[ks * 8 + sgg * 2 + 1];
        uint2 pa0 = splitpair(x0.x * q0.x, x0.y * q0.y);
        uint2 pa1 = splitpair(x0.z * q0.z, x0.w * q0.w);
        uint2 pa2 = splitpair(x1.x * q1.x, x1.y * q1.y);
        uint2 pa3 = splitpair(x1.z * q1.z, x1.w * q1.w);
        uint2 pb0 = splitpair(y0.x, y0.y);
        uint2 pb1 = splitpair(y0.z, y0.w);
        uint2 pb2 = splitpair(y1.x, y1.y);
        uint2 pb3 = splitpair(y1.z, y1.w);
        *(uint4*)(sm + soff)         = make_uint4(pa0.x, pa1.x, pa2.x, pa3.x);
        *(uint4*)(sm + 10240 + soff) = make_uint4(pa0.y, pa1.y, pa2.y, pa3.y);
        *(uint4*)(sm + 20480 + soff) = make_uint4(pb0.x, pb1.x, pb2.x, pb3.x);
        *(uint4*)(sm + 30720 + soff) = make_uint4(pb0.y, pb1.y, pb2.y, pb3.y);
        __syncthreads();
        bf16x8 ah = *(const bf16x8*)(abase);
        bf16x8 al = *(const bf16x8*)(abase + 10240);
        #pragma unroll
        for (int j = 0; j < FNW; ++j) {
            bf16x8 bh8 = *(const bf16x8*)(bbase + 1024 * j);
            bf16x8 bl8 = *(const bf16x8*)(bbase + 10240 + 1024 * j);
            acc[j] = MFMA16(ah, bh8, acc[j]);
            acc[j] = MFMA16(al, bh8, acc[j]);
            acc[j] = MFMA16(ah, bl8, acc[j]);
        }
        __syncthreads();
    }
    float* A1   = (float*)sm;
    float* wred = A1 + SS;
    float* colp = wred + 20;
    float* A2   = colp + FNW * SS;
    float* zred = A2 + SS;
    float mloc = -1e30f;
    #pragma unroll
    for (int j = 0; j < FNW; ++j)
        #pragma unroll
        for (int r = 0; r < 4; ++r) mloc = fmaxf(mloc, acc[j][r]);
    #pragma unroll
    for (int off = 32; off; off >>= 1) mloc = fmaxf(mloc, __shfl_xor(mloc, off, 64));
    if (lane == 0) wred[wid] = mloc;
    __syncthreads();
    float m = wred[0];
    #pragma unroll
    for (int w = 1; w < FNW; ++w) m = fmaxf(m, wred[w]);
    float lsum = 0.f;
    #pragma unroll
    for (int j = 0; j < FNW; ++j)
        #pragma unroll
        for (int r = 0; r < 4; ++r) {
            float e = __expf(acc[j][r] - m);
            acc[j][r] = e;
            lsum += e;
        }
    #pragma unroll
    for (int off = 32; off; off >>= 1) lsum += __shfl_xor(lsum, off, 64);
    if (lane == 0) wred[FNW + wid] = lsum;
    #pragma unroll
    for (int r = 0; r < 4; ++r) {
        float rs = 0.f;
        #pragma unroll
        for (int j = 0; j < FNW; ++j) rs += acc[j][r];
        rs += __shfl_xor(rs, 1, 64); rs += __shfl_xor(rs, 2, 64);
        rs += __shfl_xor(rs, 4, 64); rs += __shfl_xor(rs, 8, 64);
        if (n16 == 0) A1[s0 + 4 * quad + r] = rs;
    }
    #pragma unroll
    for (int j = 0; j < FNW; ++j) {
        float cs = (acc[j][0] + acc[j][1]) + (acc[j][2] + acc[j][3]);
        cs += __shfl_xor(cs, 16, 64);
        cs += __shfl_xor(cs, 32, 64);
        if (quad == 0) colp[wid * SS + 16 * j + n16] = cs;
    }
    __syncthreads();
    float l = 0.f;
    #pragma unroll
    for (int w = 0; w < FNW; ++w) l += wred[FNW + w];
    if (tid < SS) {
        float s2 = 0.f;
        #pragma unroll
        for (int w = 0; w < FNW; ++w) s2 += colp[w * SS + tid];
        A2[tid] = s2;
    }
    if (tid == 0)
        out[(size_t)NB * NH * SS * DD + (size_t)bh * SS + qi] = m + __logf(l);
    __syncthreads();
    const int d    = tid & 63;
    const int part = tid >> 6;
    const float* v1p = v1 + base;
    const float* v2p = v2 + base;
    float z = 0.f;
    #pragma unroll 4
    for (int s = part * 16; s < part * 16 + 16; ++s)
        z = fmaf(A1[s], v1p[s * DD + d], fmaf(A2[s], v2p[s * DD + d], z));
    zred[tid] = z;
    __syncthreads();
    if (tid < DD) {
        float zz = 0.f;
        #pragma unroll
        for (int kk = 0; kk < FNW; ++kk) zz += zred[tid + DD * kk];
        out[((size_t)bh * SS + qi) * DD + tid] = zz / l;
    }
}

extern "C" void kernel_launch(void* const* d_in, const int* in_sizes, int n_in,
                              void* d_out, int out_size, void* d_ws, size_t ws_size,
                              hipStream_t stream) {
    const float* q  = (const float*)d_in[0];
    const float* k1 = (const float*)d_in[1];
    const float* k2 = (const float*)d_in[2];
    const float* v1 = (const float*)d_in[3];
    const float* v2 = (const float*)d_in[4];
    float* out = (float*)d_out;
    const size_t zp_elems = (size_t)16 * 16 * SS * DD;   // [bh][chunk][q][d]
    const size_t lp_elems = (size_t)16 * 16 * SS;        // [bh][chunk][q]
    const size_t need = (zp_elems + lp_elems) * sizeof(float);
    if (ws_size >= need && d_ws != nullptr) {
        float* zp = (float*)d_ws;
        float* lp = zp + zp_elems;
        tritt_k1<<<dim3(256), dim3(640), 0, stream>>>(q, k1, k2, v1, v2, zp, lp);
        tritt_k2<<<dim3(640), dim3(256), 0, stream>>>(zp, lp, out);
    } else {
        tritt_fallback<<<dim3(NB * NH * SS), dim3(FNT), 0, stream>>>(q, k1, k2, v1, v2, out);
    }
}

// Round 10
// 172.344 us; speedup vs baseline: 1.0074x; 1.0074x over previous
//
#include <hip/hip_runtime.h>
#include <math.h>

#define NB 2
#define NH 8
#define SS 160
#define DD 64
#define MFIX 40.0f
#define NMFIXL2 -57.70780163555852f   // -MFIX * log2(e)
#define LOG2E  1.4426950408889634f

// LDS map (110400 B, 1 block/CU):
//   K2H [0,20480)       [160 t][8 grp] bf16-hi, slot g^(t&7)  (staged ONCE)
//   K2L [20480,40960)   bf16-lo
//   K1F [40960,43520)   [10 s][64 d] f32 (staged ONCE)
//   A1L [43520,56640)   [2 jh][10 sl][164 q] f32 row sums (direct stores)
//   A2  [56640,110400)  5 x [32 q][168 t] bf16
//   V2T [0,21504)       [64 d][168 t] bf16 — epilogue only, aliases dead K2
// Main loop: NO LDS writes except wave-private A1L -> NO barriers in loop.
//
// amdgpu_waves_per_eu(1): occupancy is LDS-bound at 2.5 waves/EU anyway; this
// lifts hipcc's default ~128-reg budget (4 waves/EU target) that was spilling
// the ~155-reg barrier-free body to ~250 MB of scratch (R8/R9 post-mortem).
#define K2H_OFF  0
#define K2L_OFF  20480
#define K1F_OFF  40960
#define A1L_OFF  43520
#define A1L_STR  164
#define A1L_BANK 1640
#define A2_OFF   56640
#define A2_ROWB  336
#define A2_BLKB  10752
#define V2T_OFF  0
#define V2T_ROWB 336

typedef __attribute__((ext_vector_type(8))) short bf16x8;
typedef __attribute__((ext_vector_type(4))) float f32x4;

#define MFMA16(a, b, c) __builtin_amdgcn_mfma_f32_16x16x32_bf16(a, b, c, 0, 0, 0)

// split a pair of fp32 into packed bf16 (hi, lo); lo captures the residual.
__device__ __forceinline__ uint2 splitpair(float a0, float a1) {
    unsigned u0 = __float_as_uint(a0), u1 = __float_as_uint(a1);
    unsigned hi = (u0 >> 16) | (u1 & 0xffff0000u);
    float r0 = a0 - __uint_as_float(u0 & 0xffff0000u);
    float r1 = a1 - __uint_as_float(u1 & 0xffff0000u);
    unsigned v0 = __float_as_uint(r0), v1 = __float_as_uint(r1);
    unsigned lo = (v0 >> 16) | (v1 & 0xffff0000u);
    return make_uint2(hi, lo);
}

// scores[q,(s,t)] = sum_d (q[q,d]*log2e*k1[s,d]) * k2[t,d].
// B = k2 hi/lo staged once; per tile the A-frag (q*k1[sl]) is built in regs
// from persistent f32 Q and a broadcast LDS read of k1[sl]. Barrier-free loop.
__global__ __attribute__((amdgpu_waves_per_eu(1))) __launch_bounds__(640)
void tritt_k1(
    const float* __restrict__ q,  const float* __restrict__ k1,
    const float* __restrict__ k2, const float* __restrict__ v1,
    const float* __restrict__ v2, float* __restrict__ zp, float* __restrict__ lp)
{
    __shared__ __align__(16) char sm[110400];

    const int tid  = threadIdx.x;
    const int bh   = blockIdx.x >> 4;
    const int ck   = blockIdx.x & 15;        // s-chunk: s = ck*10 + sl
    const size_t base = (size_t)bh * SS * DD;
    const int sbase = ck * 10;

    const int lane = tid & 63, wid = tid >> 6;
    const int n16  = lane & 15, quad = lane >> 4;
    const int mrow = wid >> 1;               // q strip 32*mrow .. +31
    const int jh   = wid & 1;                // t half: j = 5*jh + jj

    // ---- prologue staging (once per block) ----
    // K2 split hi/lo: 1280 (t, 8-d-group) groups
    #pragma unroll
    for (int it = 0; it < 2; ++it) {
        int f = tid + 640 * it;
        int t = f >> 3, g = f & 7;
        const float4* y = (const float4*)(k2 + base + (size_t)t * DD + g * 8);
        float4 y0 = y[0], y1 = y[1];
        uint2 p0 = splitpair(y0.x, y0.y);
        uint2 p1 = splitpair(y0.z, y0.w);
        uint2 p2 = splitpair(y1.x, y1.y);
        uint2 p3 = splitpair(y1.z, y1.w);
        char* d = sm + t * 128 + ((g ^ (t & 7)) * 16);
        *(uint4*)(d + K2H_OFF) = make_uint4(p0.x, p1.x, p2.x, p3.x);
        *(uint4*)(d + K2L_OFF) = make_uint4(p0.y, p1.y, p2.y, p3.y);
    }
    // K1 raw copy: this block's 10 rows, one f32 per thread
    {
        int r = tid >> 6, c = tid & 63;
        float v = k1[base + (size_t)(sbase + r) * DD + c];
        *(float*)(sm + K1F_OFF + r * 256 + c * 4) = v;
    }
    // Q in f32, pre-scaled by log2e (persistent, 32 regs; static indexing only)
    float qf[2][2][8];
    #pragma unroll
    for (int m = 0; m < 2; ++m)
        #pragma unroll
        for (int kc = 0; kc < 2; ++kc) {
            const float4* qp = (const float4*)(q + base
                + (size_t)(32*mrow + 16*m + n16) * DD + kc*32 + quad*8);
            float4 a = qp[0], b = qp[1];
            qf[m][kc][0] = a.x * LOG2E; qf[m][kc][1] = a.y * LOG2E;
            qf[m][kc][2] = a.z * LOG2E; qf[m][kc][3] = a.w * LOG2E;
            qf[m][kc][4] = b.x * LOG2E; qf[m][kc][5] = b.y * LOG2E;
            qf[m][kc][6] = b.z * LOG2E; qf[m][kc][7] = b.w * LOG2E;
        }
    float* A1L = (float*)(sm + A1L_OFF);
    __syncthreads();                          // LDS K2/K1F ready

    f32x4 a2run[2][5];
    #pragma unroll
    for (int m = 0; m < 2; ++m)
        #pragma unroll
        for (int jj = 0; jj < 5; ++jj) a2run[m][jj] = (f32x4){0.f,0.f,0.f,0.f};

    // ---- main loop: 10 s-tiles, NO barriers ----
    #pragma unroll 1
    for (int sl = 0; sl < 10; ++sl) {
        f32x4 acc[2][5];
        #pragma unroll
        for (int m = 0; m < 2; ++m)
            #pragma unroll
            for (int jj = 0; jj < 5; ++jj)
                acc[m][jj] = (f32x4){NMFIXL2, NMFIXL2, NMFIXL2, NMFIXL2};

        #pragma unroll
        for (int kc = 0; kc < 2; ++kc) {
            // k1[sl] broadcast read (uniform across n16 -> free)
            const float4* kv = (const float4*)(sm + K1F_OFF + sl*256 + kc*128 + quad*32);
            float4 kA = kv[0], kB = kv[1];
            // A-frags in registers: (q*log2e) * k1[sl], split hi/lo
            bf16x8 ah[2], al[2];
            #pragma unroll
            for (int m = 0; m < 2; ++m) {
                uint2 s0 = splitpair(qf[m][kc][0]*kA.x, qf[m][kc][1]*kA.y);
                uint2 s1 = splitpair(qf[m][kc][2]*kA.z, qf[m][kc][3]*kA.w);
                uint2 s2 = splitpair(qf[m][kc][4]*kB.x, qf[m][kc][5]*kB.y);
                uint2 s3 = splitpair(qf[m][kc][6]*kB.z, qf[m][kc][7]*kB.w);
                uint4 hh = make_uint4(s0.x, s1.x, s2.x, s3.x);
                uint4 ll = make_uint4(s0.y, s1.y, s2.y, s3.y);
                ah[m] = *(bf16x8*)&hh;
                al[m] = *(bf16x8*)&ll;
            }
            const int slot = ((4*kc + quad) ^ (n16 & 7)) * 16;
            #pragma unroll
            for (int jj = 0; jj < 5; ++jj) {
                const char* rb = sm + (16*(5*jh + jj) + n16) * 128 + slot;
                bf16x8 bh8 = *(const bf16x8*)(rb + K2H_OFF);
                bf16x8 bl8 = *(const bf16x8*)(rb + K2L_OFF);
                #pragma unroll
                for (int m = 0; m < 2; ++m) {
                    acc[m][jj] = MFMA16(ah[m], bh8, acc[m][jj]);
                    acc[m][jj] = MFMA16(al[m], bh8, acc[m][jj]);
                    acc[m][jj] = MFMA16(ah[m], bl8, acc[m][jj]);
                }
            }
        }

        // exp2 (shift folded into acc init); accumulate A2 + row partials
        float prs[2][4] = {{0,0,0,0},{0,0,0,0}};
        #pragma unroll
        for (int m = 0; m < 2; ++m)
            #pragma unroll
            for (int jj = 0; jj < 5; ++jj)
                #pragma unroll
                for (int r = 0; r < 4; ++r) {
                    float e = exp2f(acc[m][jj][r]);
                    a2run[m][jj][r] += e;
                    prs[m][r] += e;
                }
        // row sums over this jh-half: reduce over n16, direct store (2 banks)
        #pragma unroll
        for (int m = 0; m < 2; ++m)
            #pragma unroll
            for (int r = 0; r < 4; ++r) {
                float v = prs[m][r];
                v += __shfl_xor(v, 1, 64); v += __shfl_xor(v, 2, 64);
                v += __shfl_xor(v, 4, 64); v += __shfl_xor(v, 8, 64);
                if (n16 == 0)
                    A1L[jh*A1L_BANK + sl*A1L_STR + 32*mrow + 16*m + 4*quad + r] = v;
            }
    }

    // ---- epilogue: A2 regs -> LDS bf16 (A-frag layout) ----
    #pragma unroll
    for (int m = 0; m < 2; ++m)
        #pragma unroll
        for (int jj = 0; jj < 5; ++jj)
            #pragma unroll
            for (int r = 0; r < 4; ++r) {
                unsigned u = (__float_as_uint(a2run[m][jj][r]) + 0x8000u) >> 16;
                *(unsigned short*)(sm + A2_OFF + mrow*A2_BLKB
                    + (16*m + 4*quad + r)*A2_ROWB
                    + (16*(5*jh + jj) + n16)*2) = (unsigned short)u;
            }
    __syncthreads();    // all A1L/A2 settled; K2 region now dead

    // V2T staging (aliases dead K2): v2 -> [64 d][168 t] bf16
    {
        int t = tid >> 2, d0 = (tid & 3) * 16;
        const float4* vp = (const float4*)(v2 + base + (size_t)t * DD + d0);
        float4 a0 = vp[0], a1 = vp[1], a2v = vp[2], a3 = vp[3];
        float vals[16] = {a0.x,a0.y,a0.z,a0.w, a1.x,a1.y,a1.z,a1.w,
                          a2v.x,a2v.y,a2v.z,a2v.w, a3.x,a3.y,a3.z,a3.w};
        #pragma unroll
        for (int i = 0; i < 16; ++i) {
            unsigned u = (__float_as_uint(vals[i]) + 0x8000u) >> 16;
            *(unsigned short*)(sm + V2T_OFF + (size_t)(d0 + i)*V2T_ROWB + t*2)
                = (unsigned short)u;
        }
    }
    if (tid < SS) {
        float l = 0.f;
        #pragma unroll
        for (int s2 = 0; s2 < 10; ++s2)
            l += A1L[s2*A1L_STR + tid] + A1L[A1L_BANK + s2*A1L_STR + tid];
        lp[(size_t)(bh*16 + ck)*SS + tid] = l;
    }
    __syncthreads();

    // ---- PV: zp[q,d] = A2 @ v2 (MFMA, K=160) + A1 @ v1 (VALU) ----
    f32x4 zacc[4];
    #pragma unroll
    for (int jd = 0; jd < 4; ++jd) zacc[jd] = (f32x4){0.f,0.f,0.f,0.f};

    const char* apv = sm + A2_OFF + (wid >> 1)*A2_BLKB + ((wid & 1)*16 + n16)*A2_ROWB;
    #pragma unroll
    for (int kc = 0; kc < 5; ++kc) {
        bf16x8 af = *(const bf16x8*)(apv + (kc*32 + quad*8)*2);
        #pragma unroll
        for (int jd = 0; jd < 4; ++jd) {
            bf16x8 bfr = *(const bf16x8*)(sm + V2T_OFF + (16*jd + n16)*V2T_ROWB
                                          + (kc*32 + quad*8)*2);
            zacc[jd] = MFMA16(af, bfr, zacc[jd]);
        }
    }
    const float* v1p = v1 + base + (size_t)sbase * DD;
    #pragma unroll 1
    for (int s2 = 0; s2 < 10; ++s2) {
        int qrow = 16*wid + 4*quad;
        float a10 = A1L[s2*A1L_STR + qrow + 0] + A1L[A1L_BANK + s2*A1L_STR + qrow + 0];
        float a11 = A1L[s2*A1L_STR + qrow + 1] + A1L[A1L_BANK + s2*A1L_STR + qrow + 1];
        float a12 = A1L[s2*A1L_STR + qrow + 2] + A1L[A1L_BANK + s2*A1L_STR + qrow + 2];
        float a13 = A1L[s2*A1L_STR + qrow + 3] + A1L[A1L_BANK + s2*A1L_STR + qrow + 3];
        #pragma unroll
        for (int jd = 0; jd < 4; ++jd) {
            float vvv = v1p[s2*DD + 16*jd + n16];
            zacc[jd][0] = fmaf(a10, vvv, zacc[jd][0]);
            zacc[jd][1] = fmaf(a11, vvv, zacc[jd][1]);
            zacc[jd][2] = fmaf(a12, vvv, zacc[jd][2]);
            zacc[jd][3] = fmaf(a13, vvv, zacc[jd][3]);
        }
    }
    float* zpb = zp + (size_t)(bh*16 + ck) * SS * DD;
    #pragma unroll
    for (int jd = 0; jd < 4; ++jd)
        #pragma unroll
        for (int r = 0; r < 4; ++r)
            zpb[(16*wid + 4*quad + r)*DD + 16*jd + n16] = zacc[jd][r];
}

__global__ __launch_bounds__(256) void tritt_k2(
    const float* __restrict__ zp, const float* __restrict__ lp,
    float* __restrict__ out)
{
    int b  = blockIdx.x;                 // 640 blocks: (bh, 4-q group)
    int bh = b / 40;
    int qq = (b % 40)*4 + (threadIdx.x >> 6);
    int d  = threadIdx.x & 63;
    float zs = 0.f, ls = 0.f;
    #pragma unroll 1
    for (int c = 0; c < 16; ++c) {
        zs += zp[((size_t)(bh*16 + c)*SS + qq)*DD + d];
        ls += lp[(size_t)(bh*16 + c)*SS + qq];
    }
    out[((size_t)bh*SS + qq)*DD + d] = zs / ls;
    if (d == 0)
        out[(size_t)NB*NH*SS*DD + (size_t)bh*SS + qq] = MFIX + __logf(ls);
}

// ====================== fallback (round-1 kernel, verified) ======================
#define FNT 640
#define FNW 10
__global__ __launch_bounds__(FNT, 5) void tritt_fallback(
    const float* __restrict__ q,  const float* __restrict__ k1,
    const float* __restrict__ k2, const float* __restrict__ v1,
    const float* __restrict__ v2, float* __restrict__ out)
{
    __shared__ __align__(16) char sm[40960];
    const int tid = threadIdx.x;
    const int blk = blockIdx.x;
    const int bh  = blk / SS;
    const int qi  = blk % SS;
    const size_t base = (size_t)bh * SS * DD;
    const float4* k1f = (const float4*)(k1 + base);
    const float4* k2f = (const float4*)(k2 + base);
    const float4* qf  = (const float4*)(q + base + (size_t)qi * DD);
    const int lane = tid & 63;
    const int wid  = tid >> 6;
    const int n16  = lane & 15, quad = lane >> 4;
    const int s0   = 16 * wid;
    const int ssg  = tid >> 2;
    const int sgg  = tid & 3;
    const int soff = ssg * 64 + ((sgg ^ (ssg & 3)) * 16);
    const char* abase = sm + (s0 + n16) * 64 + ((quad ^ (n16 & 3)) * 16);
    const char* bbase = sm + 20480 + n16 * 64 + ((quad ^ (n16 & 3)) * 16);
    f32x4 acc[FNW];
    #pragma unroll
    for (int j = 0; j < FNW; ++j) acc[j] = (f32x4){0.f, 0.f, 0.f, 0.f};
    #pragma unroll
    for (int ks = 0; ks < 2; ++ks) {
        int fg = ssg * 16 + ks * 8 + sgg * 2;
        float4 x0 = k1f[fg], x1 = k1f[fg + 1];
        float4 y0 = k2f[fg], y1 = k2f[fg + 1];
        float4 q0 = qf[ks * 8 + sgg * 2], q1 = qf[ks * 8 + sgg * 2 + 1];
        uint2 pa0 = splitpair(x0.x * q0.x, x0.y * q0.y);
        uint2 pa1 = splitpair(x0.z * q0.z, x0.w * q0.w);
        uint2 pa2 = splitpair(x1.x * q1.x, x1.y * q1.y);
        uint2 pa3 = splitpair(x1.z * q1.z, x1.w * q1.w);
        uint2 pb0 = splitpair(y0.x, y0.y);
        uint2 pb1 = splitpair(y0.z, y0.w);
        uint2 pb2 = splitpair(y1.x, y1.y);
        uint2 pb3 = splitpair(y1.z, y1.w);
        *(uint4*)(sm + soff)         = make_uint4(pa0.x, pa1.x, pa2.x, pa3.x);
        *(uint4*)(sm + 10240 + soff) = make_uint4(pa0.y, pa1.y, pa2.y, pa3.y);
        *(uint4*)(sm + 20480 + soff) = make_uint4(pb0.x, pb1.x, pb2.x, pb3.x);
        *(uint4*)(sm + 30720 + soff) = make_uint4(pb0.y, pb1.y, pb2.y, pb3.y);
        __syncthreads();
        bf16x8 ah = *(const bf16x8*)(abase);
        bf16x8 al = *(const bf16x8*)(abase + 10240);
        #pragma unroll
        for (int j = 0; j < FNW; ++j) {
            bf16x8 bh8 = *(const bf16x8*)(bbase + 1024 * j);
            bf16x8 bl8 = *(const bf16x8*)(bbase + 10240 + 1024 * j);
            acc[j] = MFMA16(ah, bh8, acc[j]);
            acc[j] = MFMA16(al, bh8, acc[j]);
            acc[j] = MFMA16(ah, bl8, acc[j]);
        }
        __syncthreads();
    }
    float* A1   = (float*)sm;
    float* wred = A1 + SS;
    float* colp = wred + 20;
    float* A2   = colp + FNW * SS;
    float* zred = A2 + SS;
    float mloc = -1e30f;
    #pragma unroll
    for (int j = 0; j < FNW; ++j)
        #pragma unroll
        for (int r = 0; r < 4; ++r) mloc = fmaxf(mloc, acc[j][r]);
    #pragma unroll
    for (int off = 32; off; off >>= 1) mloc = fmaxf(mloc, __shfl_xor(mloc, off, 64));
    if (lane == 0) wred[wid] = mloc;
    __syncthreads();
    float m = wred[0];
    #pragma unroll
    for (int w = 1; w < FNW; ++w) m = fmaxf(m, wred[w]);
    float lsum = 0.f;
    #pragma unroll
    for (int j = 0; j < FNW; ++j)
        #pragma unroll
        for (int r = 0; r < 4; ++r) {
            float e = __expf(acc[j][r] - m);
            acc[j][r] = e;
            lsum += e;
        }
    #pragma unroll
    for (int off = 32; off; off >>= 1) lsum += __shfl_xor(lsum, off, 64);
    if (lane == 0) wred[FNW + wid] = lsum;
    #pragma unroll
    for (int r = 0; r < 4; ++r) {
        float rs = 0.f;
        #pragma unroll
        for (int j = 0; j < FNW; ++j) rs += acc[j][r];
        rs += __shfl_xor(rs, 1, 64); rs += __shfl_xor(rs, 2, 64);
        rs += __shfl_xor(rs, 4, 64); rs += __shfl_xor(rs, 8, 64);
        if (n16 == 0) A1[s0 + 4 * quad + r] = rs;
    }
    #pragma unroll
    for (int j = 0; j < FNW; ++j) {
        float cs = (acc[j][0] + acc[j][1]) + (acc[j][2] + acc[j][3]);
        cs += __shfl_xor(cs, 16, 64);
        cs += __shfl_xor(cs, 32, 64);
        if (quad == 0) colp[wid * SS + 16 * j + n16] = cs;
    }
    __syncthreads();
    float l = 0.f;
    #pragma unroll
    for (int w = 0; w < FNW; ++w) l += wred[FNW + w];
    if (tid < SS) {
        float s2 = 0.f;
        #pragma unroll
        for (int w = 0; w < FNW; ++w) s2 += colp[w * SS + tid];
        A2[tid] = s2;
    }
    if (tid == 0)
        out[(size_t)NB * NH * SS * DD + (size_t)bh * SS + qi] = m + __logf(l);
    __syncthreads();
    const int d    = tid & 63;
    const int part = tid >> 6;
    const float* v1p = v1 + base;
    const float* v2p = v2 + base;
    float z = 0.f;
    #pragma unroll 4
    for (int s = part * 16; s < part * 16 + 16; ++s)
        z = fmaf(A1[s], v1p[s * DD + d], fmaf(A2[s], v2p[s * DD + d], z));
    zred[tid] = z;
    __syncthreads();
    if (tid < DD) {
        float zz = 0.f;
        #pragma unroll
        for (int kk = 0; kk < FNW; ++kk) zz += zred[tid + DD * kk];
        out[((size_t)bh * SS + qi) * DD + tid] = zz / l;
    }
}

extern "C" void kernel_launch(void* const* d_in, const int* in_sizes, int n_in,
                              void* d_out, int out_size, void* d_ws, size_t ws_size,
                              hipStream_t stream) {
    const float* q  = (const float*)d_in[0];
    const float* k1 = (const float*)d_in[1];
    const float* k2 = (const float*)d_in[2];
    const float* v1 = (const float*)d_in[3];
    const float* v2 = (const float*)d_in[4];
    float* out = (float*)d_out;
    const size_t zp_elems = (size_t)16 * 16 * SS * DD;   // [bh][chunk][q][d]
    const size_t lp_elems = (size_t)16 * 16 * SS;        // [bh][chunk][q]
    const size_t need = (zp_elems + lp_elems) * sizeof(float);
    if (ws_size >= need && d_ws != nullptr) {
        float* zp = (float*)d_ws;
        float* lp = zp + zp_elems;
        tritt_k1<<<dim3(256), dim3(640), 0, stream>>>(q, k1, k2, v1, v2, zp, lp);
        tritt_k2<<<dim3(640), dim3(256), 0, stream>>>(zp, lp, out);
    } else {
        tritt_fallback<<<dim3(NB * NH * SS), dim3(FNT), 0, stream>>>(q, k1, k2, v1, v2, out);
    }
}

// Round 11
// 141.355 us; speedup vs baseline: 1.2282x; 1.2192x over previous
//
#include <hip/hip_runtime.h>
#include <math.h>

#define NB 2
#define NH 8
#define SS 160
#define DD 64
#define MFIX 40.0f
#define NMFIXL2 -57.70780163555852f   // -MFIX * log2(e)
#define LOG2E  1.4426950408889634f

// k1 LDS map — COMPACT (54176 B total -> 2 blocks/CU co-resident; R3's layout
// put A1L at 75360 -> 81920 B -> 2x81920 = exactly 160 KiB, which failed to
// co-schedule; that was the entire reason R3 saw no occupancy gain):
//   main loop : WB0 [0,20480) (hi 10240 + lo 10240)  WB1 [20480,40960)
//               A1L [47616,54176) = [10 sl][164 q] f32 direct stores
//   epilogue  : V2T [0,13312) aliases WB0 (dead at sl=9; compute uses WB1)
//               A2  [13312,46592) aliases WB1 (dead after final barrier)
#define WB_SZ    20480
#define WB_HALF  10240
#define PV_ROWB  208             // 104 bf16 slots/row; K padded 80->96
#define V2T_OFF  0
#define A2_OFF   13312
#define A1L_OFF  47616
#define A1L_STR  164

typedef __attribute__((ext_vector_type(8))) short bf16x8;
typedef __attribute__((ext_vector_type(4))) float f32x4;

#define MFMA16(a, b, c) __builtin_amdgcn_mfma_f32_16x16x32_bf16(a, b, c, 0, 0, 0)

// split a pair of fp32 into packed bf16 (hi, lo); lo captures the residual.
__device__ __forceinline__ uint2 splitpair(float a0, float a1) {
    unsigned u0 = __float_as_uint(a0), u1 = __float_as_uint(a1);
    unsigned hi = (u0 >> 16) | (u1 & 0xffff0000u);
    float r0 = a0 - __uint_as_float(u0 & 0xffff0000u);
    float r1 = a1 - __uint_as_float(u1 & 0xffff0000u);
    unsigned v0 = __float_as_uint(r0), v1 = __float_as_uint(r1);
    unsigned lo = (v0 >> 16) | (v1 & 0xffff0000u);
    return make_uint2(hi, lo);
}

// Block = (bh, s-chunk of 10, t-half of 80). 512 blocks, 10 waves each; wave
// owns 16 q rows x 80 t (acc 20 + a2run 20 AGPR, VGPR 48 — fits 5 waves/EU).
// W[(s,t),d]=k1[s,d]k2[t,d] staged per-s as bf16 hi/lo (3-term MFMA), exp2
// folding (Q pre-scaled log2e, acc init -MFIX*log2e). Partials -> zp/lp.
__global__ __launch_bounds__(640, 5) void tritt_k1(
    const float* __restrict__ q,  const float* __restrict__ k1,
    const float* __restrict__ k2, const float* __restrict__ v1,
    const float* __restrict__ v2, float* __restrict__ zp, float* __restrict__ lp)
{
    __shared__ __align__(16) char sm[54176];

    const int tid  = threadIdx.x;
    const int bh   = blockIdx.x >> 5;
    const int cidx = blockIdx.x & 31;       // 32 partials per bh
    const int sck  = cidx >> 1;             // s in [10*sck, +10)
    const int th   = cidx & 1;              // t in [80*th, +80)
    const size_t base = (size_t)bh * SS * DD;
    const int t0 = 80 * th, sbase = 10 * sck;

    const int lane = tid & 63, wid = tid >> 6;
    const int n16  = lane & 15, quad = lane >> 4;

    // ---- Q fragments scaled by log2e (persistent): row 16*wid+n16 ----
    bf16x8 qh[2], ql[2];
    #pragma unroll
    for (int kc = 0; kc < 2; ++kc) {
        const float4* qp = (const float4*)(q + base
            + (size_t)(16*wid + n16) * DD + kc*32 + quad*8);
        float4 a = qp[0], b = qp[1];
        uint2 p0 = splitpair(a.x*LOG2E, a.y*LOG2E), p1 = splitpair(a.z*LOG2E, a.w*LOG2E);
        uint2 p2 = splitpair(b.x*LOG2E, b.y*LOG2E), p3 = splitpair(b.z*LOG2E, b.w*LOG2E);
        uint4 hh = make_uint4(p0.x, p1.x, p2.x, p3.x);
        uint4 ll = make_uint4(p0.y, p1.y, p2.y, p3.y);
        qh[kc] = *(bf16x8*)&hh;
        ql[kc] = *(bf16x8*)&ll;
    }

    // ---- staging: one (t, 8-d group) per thread ----
    const int st = tid >> 3, sg = tid & 7;
    auto stageW = [&](int sl) {             // tile s = sbase+sl -> buf sl&1
        char* dst = sm + (sl & 1) * WB_SZ;
        const float4* yp = (const float4*)(k2 + base + (size_t)(t0 + st) * DD + sg*8);
        const float4* xp = (const float4*)(k1 + base + (size_t)(sbase + sl) * DD + sg*8);
        float4 y0 = yp[0], y1 = yp[1], x0 = xp[0], x1 = xp[1];
        uint2 p0 = splitpair(x0.x*y0.x, x0.y*y0.y);
        uint2 p1 = splitpair(x0.z*y0.z, x0.w*y0.w);
        uint2 p2 = splitpair(x1.x*y1.x, x1.y*y1.y);
        uint2 p3 = splitpair(x1.z*y1.z, x1.w*y1.w);
        char* d = dst + st*128 + ((sg ^ (st & 7)) * 16);
        *(uint4*)d             = make_uint4(p0.x, p1.x, p2.x, p3.x);
        *(uint4*)(d + WB_HALF) = make_uint4(p0.y, p1.y, p2.y, p3.y);
    };
    auto stageV2T = [&]() {                 // v2 half -> [64 d][PV rows] bf16
        const float4* vp = (const float4*)(v2 + base + (size_t)(t0 + st) * DD + sg*8);
        float4 a = vp[0], b = vp[1];
        float vals[8] = {a.x,a.y,a.z,a.w, b.x,b.y,b.z,b.w};
        #pragma unroll
        for (int i = 0; i < 8; ++i) {
            unsigned u = (__float_as_uint(vals[i]) + 0x8000u) >> 16;
            *(unsigned short*)(sm + V2T_OFF + (size_t)(sg*8 + i)*PV_ROWB + st*2)
                = (unsigned short)u;
        }
    };

    float* A1L = (float*)(sm + A1L_OFF);    // [10 s][164] partial row sums

    stageW(0);
    __syncthreads();

    f32x4 a2run[5];
    #pragma unroll
    for (int jj = 0; jj < 5; ++jj) a2run[jj] = (f32x4){0.f,0.f,0.f,0.f};

    const int slot0 = (quad ^ (n16 & 7)) * 16;
    const int slot1 = ((4 + quad) ^ (n16 & 7)) * 16;

    // ---- main loop: 10 s-tiles, double-buffered W, 1 barrier/tile ----
    #pragma unroll 1
    for (int sl = 0; sl < 10; ++sl) {
        if (sl < 9) stageW(sl + 1); else stageV2T();    // overlaps with compute

        const char* wb = sm + (sl & 1) * WB_SZ;
        f32x4 acc[5];
        #pragma unroll
        for (int jj = 0; jj < 5; ++jj)
            acc[jj] = (f32x4){NMFIXL2, NMFIXL2, NMFIXL2, NMFIXL2};

        #pragma unroll
        for (int jj = 0; jj < 5; ++jj) {
            const char* rb = wb + (16*jj + n16) * 128;
            bf16x8 wh0 = *(const bf16x8*)(rb + slot0);
            bf16x8 wl0 = *(const bf16x8*)(rb + slot0 + WB_HALF);
            bf16x8 wh1 = *(const bf16x8*)(rb + slot1);
            bf16x8 wl1 = *(const bf16x8*)(rb + slot1 + WB_HALF);
            acc[jj] = MFMA16(qh[0], wh0, acc[jj]);
            acc[jj] = MFMA16(ql[0], wh0, acc[jj]);
            acc[jj] = MFMA16(qh[0], wl0, acc[jj]);
            acc[jj] = MFMA16(qh[1], wh1, acc[jj]);
            acc[jj] = MFMA16(ql[1], wh1, acc[jj]);
            acc[jj] = MFMA16(qh[1], wl1, acc[jj]);
        }

        // exp2 (shift folded into acc init); accumulate A2 + row partials
        float prs[4] = {0.f, 0.f, 0.f, 0.f};
        #pragma unroll
        for (int jj = 0; jj < 5; ++jj)
            #pragma unroll
            for (int r = 0; r < 4; ++r) {
                float e = exp2f(acc[jj][r]);
                a2run[jj][r] += e;
                prs[r] += e;
            }
        // full row (80 t) lives in this wave: reduce over n16, direct store
        #pragma unroll
        for (int r = 0; r < 4; ++r) {
            float v = prs[r];
            v += __shfl_xor(v, 1, 64); v += __shfl_xor(v, 2, 64);
            v += __shfl_xor(v, 4, 64); v += __shfl_xor(v, 8, 64);
            if (n16 == 0) A1L[sl*A1L_STR + 16*wid + 4*quad + r] = v;
        }
        __syncthreads();
    }

    // ---- epilogue phase 1: A2 -> LDS bf16, zero K-pads, lp ----
    #pragma unroll
    for (int jj = 0; jj < 5; ++jj)
        #pragma unroll
        for (int r = 0; r < 4; ++r) {
            unsigned u = (__float_as_uint(a2run[jj][r]) + 0x8000u) >> 16;
            *(unsigned short*)(sm + A2_OFF + (16*wid + 4*quad + r)*PV_ROWB
                               + (16*jj + n16)*2) = (unsigned short)u;
        }
    #pragma unroll
    for (int i = tid; i < 160*8; i += 640) {          // A2 cols 80..95 = 0
        int qq = i >> 3, w = i & 7;
        *(unsigned*)(sm + A2_OFF + qq*PV_ROWB + 160 + w*4) = 0u;
    }
    if (tid < 64*8) {                                  // V2T cols 80..95 = 0
        int dd2 = tid >> 3, w = tid & 7;
        *(unsigned*)(sm + V2T_OFF + dd2*PV_ROWB + 160 + w*4) = 0u;
    }
    if (tid < SS) {
        float l = 0.f;
        #pragma unroll
        for (int s2 = 0; s2 < 10; ++s2) l += A1L[s2*A1L_STR + tid];
        lp[(size_t)(bh*32 + cidx)*SS + tid] = l;
    }
    __syncthreads();

    // ---- PV: zacc[q,d] = A2 @ v2 (MFMA, K=96 padded) + A1 @ v1 (VALU) ----
    f32x4 zacc[4];
    #pragma unroll
    for (int jd = 0; jd < 4; ++jd) zacc[jd] = (f32x4){0.f,0.f,0.f,0.f};

    const char* ap = sm + A2_OFF + (16*wid + n16)*PV_ROWB;
    #pragma unroll
    for (int kc = 0; kc < 3; ++kc) {
        bf16x8 af = *(const bf16x8*)(ap + (kc*32 + quad*8)*2);
        #pragma unroll
        for (int jd = 0; jd < 4; ++jd) {
            bf16x8 bfr = *(const bf16x8*)(sm + V2T_OFF + (16*jd + n16)*PV_ROWB
                                          + (kc*32 + quad*8)*2);
            zacc[jd] = MFMA16(af, bfr, zacc[jd]);
        }
    }
    const float* v1p = v1 + base + (size_t)sbase * DD;
    #pragma unroll 1
    for (int s2 = 0; s2 < 10; ++s2) {
        float a10 = A1L[s2*A1L_STR + 16*wid + 4*quad + 0];
        float a11 = A1L[s2*A1L_STR + 16*wid + 4*quad + 1];
        float a12 = A1L[s2*A1L_STR + 16*wid + 4*quad + 2];
        float a13 = A1L[s2*A1L_STR + 16*wid + 4*quad + 3];
        #pragma unroll
        for (int jd = 0; jd < 4; ++jd) {
            float vv = v1p[s2*DD + 16*jd + n16];
            zacc[jd][0] = fmaf(a10, vv, zacc[jd][0]);
            zacc[jd][1] = fmaf(a11, vv, zacc[jd][1]);
            zacc[jd][2] = fmaf(a12, vv, zacc[jd][2]);
            zacc[jd][3] = fmaf(a13, vv, zacc[jd][3]);
        }
    }
    float* zpb = zp + (size_t)(bh*32 + cidx) * SS * DD;
    #pragma unroll
    for (int jd = 0; jd < 4; ++jd)
        #pragma unroll
        for (int r = 0; r < 4; ++r)
            zpb[(16*wid + 4*quad + r)*DD + 16*jd + n16] = zacc[jd][r];
}

__global__ __launch_bounds__(256) void tritt_k2(
    const float* __restrict__ zp, const float* __restrict__ lp,
    float* __restrict__ out)
{
    int b  = blockIdx.x;                 // 640 blocks: (bh, 4-q group)
    int bh = b / 40;
    int qq = (b % 40)*4 + (threadIdx.x >> 6);
    int d  = threadIdx.x & 63;
    float zs = 0.f, ls = 0.f;
    #pragma unroll 1
    for (int c = 0; c < 32; ++c) {
        zs += zp[((size_t)(bh*32 + c)*SS + qq)*DD + d];
        ls += lp[(size_t)(bh*32 + c)*SS + qq];
    }
    out[((size_t)bh*SS + qq)*DD + d] = zs / ls;
    if (d == 0)
        out[(size_t)NB*NH*SS*DD + (size_t)bh*SS + qq] = MFIX + __logf(ls);
}

// ====================== fallback (round-1 kernel, verified) ======================
#define FNT 640
#define FNW 10
__global__ __launch_bounds__(FNT, 5) void tritt_fallback(
    const float* __restrict__ q,  const float* __restrict__ k1,
    const float* __restrict__ k2, const float* __restrict__ v1,
    const float* __restrict__ v2, float* __restrict__ out)
{
    __shared__ __align__(16) char sm[40960];
    const int tid = threadIdx.x;
    const int blk = blockIdx.x;
    const int bh  = blk / SS;
    const int qi  = blk % SS;
    const size_t base = (size_t)bh * SS * DD;
    const float4* k1f = (const float4*)(k1 + base);
    const float4* k2f = (const float4*)(k2 + base);
    const float4* qf  = (const float4*)(q + base + (size_t)qi * DD);
    const int lane = tid & 63;
    const int wid  = tid >> 6;
    const int n16  = lane & 15, quad = lane >> 4;
    const int s0   = 16 * wid;
    const int ssg  = tid >> 2;
    const int sgg  = tid & 3;
    const int soff = ssg * 64 + ((sgg ^ (ssg & 3)) * 16);
    const char* abase = sm + (s0 + n16) * 64 + ((quad ^ (n16 & 3)) * 16);
    const char* bbase = sm + 20480 + n16 * 64 + ((quad ^ (n16 & 3)) * 16);
    f32x4 acc[FNW];
    #pragma unroll
    for (int j = 0; j < FNW; ++j) acc[j] = (f32x4){0.f, 0.f, 0.f, 0.f};
    #pragma unroll
    for (int ks = 0; ks < 2; ++ks) {
        int fg = ssg * 16 + ks * 8 + sgg * 2;
        float4 x0 = k1f[fg], x1 = k1f[fg + 1];
        float4 y0 = k2f[fg], y1 = k2f[fg + 1];
        float4 q0 = qf[ks * 8 + sgg * 2], q1 = qf[ks * 8 + sgg * 2 + 1];
        uint2 pa0 = splitpair(x0.x * q0.x, x0.y * q0.y);
        uint2 pa1 = splitpair(x0.z * q0.z, x0.w * q0.w);
        uint2 pa2 = splitpair(x1.x * q1.x, x1.y * q1.y);
        uint2 pa3 = splitpair(x1.z * q1.z, x1.w * q1.w);
        uint2 pb0 = splitpair(y0.x, y0.y);
        uint2 pb1 = splitpair(y0.z, y0.w);
        uint2 pb2 = splitpair(y1.x, y1.y);
        uint2 pb3 = splitpair(y1.z, y1.w);
        *(uint4*)(sm + soff)         = make_uint4(pa0.x, pa1.x, pa2.x, pa3.x);
        *(uint4*)(sm + 10240 + soff) = make_uint4(pa0.y, pa1.y, pa2.y, pa3.y);
        *(uint4*)(sm + 20480 + soff) = make_uint4(pb0.x, pb1.x, pb2.x, pb3.x);
        *(uint4*)(sm + 30720 + soff) = make_uint4(pb0.y, pb1.y, pb2.y, pb3.y);
        __syncthreads();
        bf16x8 ah = *(const bf16x8*)(abase);
        bf16x8 al = *(const bf16x8*)(abase + 10240);
        #pragma unroll
        for (int j = 0; j < FNW; ++j) {
            bf16x8 bh8 = *(const bf16x8*)(bbase + 1024 * j);
            bf16x8 bl8 = *(const bf16x8*)(bbase + 10240 + 1024 * j);
            acc[j] = MFMA16(ah, bh8, acc[j]);
            acc[j] = MFMA16(al, bh8, acc[j]);
            acc[j] = MFMA16(ah, bl8, acc[j]);
        }
        __syncthreads();
    }
    float* A1   = (float*)sm;
    float* wred = A1 + SS;
    float* colp = wred + 20;
    float* A2   = colp + FNW * SS;
    float* zred = A2 + SS;
    float mloc = -1e30f;
    #pragma unroll
    for (int j = 0; j < FNW; ++j)
        #pragma unroll
        for (int r = 0; r < 4; ++r) mloc = fmaxf(mloc, acc[j][r]);
    #pragma unroll
    for (int off = 32; off; off >>= 1) mloc = fmaxf(mloc, __shfl_xor(mloc, off, 64));
    if (lane == 0) wred[wid] = mloc;
    __syncthreads();
    float m = wred[0];
    #pragma unroll
    for (int w = 1; w < FNW; ++w) m = fmaxf(m, wred[w]);
    float lsum = 0.f;
    #pragma unroll
    for (int j = 0; j < FNW; ++j)
        #pragma unroll
        for (int r = 0; r < 4; ++r) {
            float e = __expf(acc[j][r] - m);
            acc[j][r] = e;
            lsum += e;
        }
    #pragma unroll
    for (int off = 32; off; off >>= 1) lsum += __shfl_xor(lsum, off, 64);
    if (lane == 0) wred[FNW + wid] = lsum;
    #pragma unroll
    for (int r = 0; r < 4; ++r) {
        float rs = 0.f;
        #pragma unroll
        for (int j = 0; j < FNW; ++j) rs += acc[j][r];
        rs += __shfl_xor(rs, 1, 64); rs += __shfl_xor(rs, 2, 64);
        rs += __shfl_xor(rs, 4, 64); rs += __shfl_xor(rs, 8, 64);
        if (n16 == 0) A1[s0 + 4 * quad + r] = rs;
    }
    #pragma unroll
    for (int j = 0; j < FNW; ++j) {
        float cs = (acc[j][0] + acc[j][1]) + (acc[j][2] + acc[j][3]);
        cs += __shfl_xor(cs, 16, 64);
        cs += __shfl_xor(cs, 32, 64);
        if (quad == 0) colp[wid * SS + 16 * j + n16] = cs;
    }
    __syncthreads();
    float l = 0.f;
    #pragma unroll
    for (int w = 0; w < FNW; ++w) l += wred[FNW + w];
    if (tid < SS) {
        float s2 = 0.f;
        #pragma unroll
        for (int w = 0; w < FNW; ++w) s2 += colp[w * SS + tid];
        A2[tid] = s2;
    }
    if (tid == 0)
        out[(size_t)NB * NH * SS * DD + (size_t)bh * SS + qi] = m + __logf(l);
    __syncthreads();
    const int d    = tid & 63;
    const int part = tid >> 6;
    const float* v1p = v1 + base;
    const float* v2p = v2 + base;
    float z = 0.f;
    #pragma unroll 4
    for (int s = part * 16; s < part * 16 + 16; ++s)
        z = fmaf(A1[s], v1p[s * DD + d], fmaf(A2[s], v2p[s * DD + d], z));
    zred[tid] = z;
    __syncthreads();
    if (tid < DD) {
        float zz = 0.f;
        #pragma unroll
        for (int kk = 0; kk < FNW; ++kk) zz += zred[tid + DD * kk];
        out[((size_t)bh * SS + qi) * DD + tid] = zz / l;
    }
}

extern "C" void kernel_launch(void* const* d_in, const int* in_sizes, int n_in,
                              void* d_out, int out_size, void* d_ws, size_t ws_size,
                              hipStream_t stream) {
    const float* q  = (const float*)d_in[0];
    const float* k1 = (const float*)d_in[1];
    const float* k2 = (const float*)d_in[2];
    const float* v1 = (const float*)d_in[3];
    const float* v2 = (const float*)d_in[4];
    float* out = (float*)d_out;
    const size_t zp_elems = (size_t)16 * 32 * SS * DD;   // [bh][partial][q][d]
    const size_t lp_elems = (size_t)16 * 32 * SS;        // [bh][partial][q]
    const size_t need = (zp_elems + lp_elems) * sizeof(float);
    if (ws_size >= need && d_ws != nullptr) {
        float* zp = (float*)d_ws;
        float* lp = zp + zp_elems;
        tritt_k1<<<dim3(512), dim3(640), 0, stream>>>(q, k1, k2, v1, v2, zp, lp);
        tritt_k2<<<dim3(640), dim3(256), 0, stream>>>(zp, lp, out);
    } else {
        tritt_fallback<<<dim3(NB * NH * SS), dim3(FNT), 0, stream>>>(q, k1, k2, v1, v2, out);
    }
}